// Round 13
// baseline (576.574 us; speedup 1.0000x reference)
//
#include <hip/hip_runtime.h>
#include <math.h>

#define N_NODES 30000
#define N_EDGES 240000
#define E2 (N_EDGES + N_NODES)   // 270000 with self-loops
#define D 128
#define LAYERS 6
#define NEG_SLOPE 0.2f
#define LN_EPS 1e-5f

typedef unsigned short u16;
typedef unsigned int u32;
using bfrag = __attribute__((ext_vector_type(8))) short;
using f32x4 = __attribute__((ext_vector_type(4))) float;
using u32x4 = __attribute__((ext_vector_type(4))) unsigned int;

__device__ inline u16 f2bf(float f) {
    u32 u = __float_as_uint(f);
    u32 r = u + 0x7fffu + ((u >> 16) & 1u);
    return (u16)(r >> 16);
}
__device__ inline u32 pack2(float a, float b) { return (u32)f2bf(a) | ((u32)f2bf(b) << 16); }
__device__ inline float bflo(u32 u) { return __uint_as_float(u << 16); }
__device__ inline float bfhi(u32 u) { return __uint_as_float(u & 0xffff0000u); }
__device__ inline u32 bfadd2(u32 a, u32 b) {
    return pack2(bflo(a) + bflo(b), bfhi(a) + bfhi(b));
}

// 16-lane sum reduce via DPP (VALU-speed): xor1 (0xB1), xor2 (0x4E),
// row_half_mirror (0x141), row_mirror (0x140).
__device__ inline float red16_dpp(float x) {
    x += __int_as_float(__builtin_amdgcn_update_dpp(0, __float_as_int(x), 0xB1, 0xF, 0xF, true));
    x += __int_as_float(__builtin_amdgcn_update_dpp(0, __float_as_int(x), 0x4E, 0xF, 0xF, true));
    x += __int_as_float(__builtin_amdgcn_update_dpp(0, __float_as_int(x), 0x141, 0xF, 0xF, true));
    x += __int_as_float(__builtin_amdgcn_update_dpp(0, __float_as_int(x), 0x140, 0xF, 0xF, true));
    return x;
}

// ---------------- weight prep: Wt[b][n][k] = bf16(W[b][k][n]) ----------------
__global__ __launch_bounds__(256) void wt_convert(const float* __restrict__ Wl,
        const float* __restrict__ Wr, const float* __restrict__ linW, u16* __restrict__ wt)
{
    __shared__ u16 tile[128 * 129];
    int b = blockIdx.x;
    const float* src = (b == 12) ? linW
                     : ((b & 1) ? Wr + (size_t)(b >> 1) * 16384 : Wl + (size_t)(b >> 1) * 16384);
    int t = threadIdx.x;
    #pragma unroll 4
    for (int i = 0; i < 64; i++) {
        int idx = t + 256 * i;           // idx = k*128 + n
        int k = idx >> 7, n = idx & 127;
        tile[n * 129 + k] = f2bf(src[idx]);
    }
    __syncthreads();
    u16* dst = wt + (size_t)b * 16384;
    #pragma unroll 4
    for (int i = 0; i < 64; i++) {
        int idx = t + 256 * i;           // idx = n*128 + k
        int n = idx >> 7, k = idx & 127;
        dst[idx] = tile[n * 129 + k];
    }
}

// ---------------- CSR build (by dst) ----------------
__global__ __launch_bounds__(256) void hist_kernel(const int* __restrict__ ei, int* __restrict__ cnt)
{
    int e = blockIdx.x * 256 + threadIdx.x;
    if (e >= E2) return;
    int d = (e < N_EDGES) ? ei[N_EDGES + e] : (e - N_EDGES);
    atomicAdd(&cnt[d], 1);
}

__global__ __launch_bounds__(1024) void scan1_kernel(const int* __restrict__ cnt,
        int* __restrict__ lscan, int* __restrict__ bsum)
{
    __shared__ int wtot[16];
    int t = threadIdx.x, lane = t & 63, w = t >> 6;
    int i = blockIdx.x * 1024 + t;
    int v = (i < N_NODES) ? cnt[i] : 0;
    int s = v;
    #pragma unroll
    for (int off = 1; off < 64; off <<= 1) {
        int u = __shfl_up(s, off);
        if (lane >= off) s += u;
    }
    if (lane == 63) wtot[w] = s;
    __syncthreads();
    if (t < 16) {
        int xv = wtot[t];
        #pragma unroll
        for (int off = 1; off < 16; off <<= 1) {
            int u = __shfl_up(xv, off);
            if (t >= off) xv += u;
        }
        wtot[t] = xv;
    }
    __syncthreads();
    int incl = ((w == 0) ? 0 : wtot[w - 1]) + s;
    if (i < N_NODES) lscan[i] = incl;
    if (t == 0) bsum[blockIdx.x] = wtot[15];
}

// scan3 with integrated 30-element block-offset scan
__global__ __launch_bounds__(1024) void scan3_kernel(const int* __restrict__ lscan,
        const int* __restrict__ bsum, const int* __restrict__ cnt,
        int* __restrict__ row_off, int* __restrict__ cursor)
{
    __shared__ int sboff;
    if (threadIdx.x < 64) {
        int v = (threadIdx.x < 30) ? bsum[threadIdx.x] : 0;
        int s = v;
        #pragma unroll
        for (int off = 1; off < 64; off <<= 1) {
            int u = __shfl_up(s, off);
            if ((int)threadIdx.x >= off) s += u;
        }
        if (threadIdx.x == blockIdx.x) sboff = s - v;   // exclusive prefix
    }
    __syncthreads();
    int i = blockIdx.x * 1024 + threadIdx.x;
    if (i == 0) row_off[0] = 0;
    if (i < N_NODES) {
        int r = lscan[i] + sboff;
        row_off[i + 1] = r;
        cursor[i] = r - cnt[i];
    }
}

__global__ __launch_bounds__(256) void scatter_kernel(const int* __restrict__ ei,
        int* __restrict__ cursor, int* __restrict__ csr_src)
{
    int e = blockIdx.x * 256 + threadIdx.x;
    if (e >= E2) return;
    int s, d;
    if (e < N_EDGES) { s = ei[e]; d = ei[N_EDGES + e]; }
    else             { s = e - N_EDGES; d = s; }
    int pos = atomicAdd(&cursor[d], 1);
    csr_src[pos] = s;
}

// ---------------- per-node src-sort (R12): ascending src => all concurrent waves
// sweep a narrow src window => gather working set fits per-XCD L2 ----------------
__global__ __launch_bounds__(256) void sort_kernel(const int* __restrict__ row_off,
        int* __restrict__ csr_src)
{
    int n = blockIdx.x * 256 + threadIdx.x;
    if (n >= N_NODES) return;
    int s0 = row_off[n], s1 = row_off[n + 1];
    int d = s1 - s0;
    if (d <= 1 || d > 48) return;    // deg ~ 1+Poisson(8); P(>48) ~ 0
    int buf[48];
    for (int i = 0; i < d; i++) buf[i] = csr_src[s0 + i];
    for (int i = 1; i < d; i++) {
        int key = buf[i], j = i - 1;
        while (j >= 0 && buf[j] > key) { buf[j + 1] = buf[j]; j--; }
        buf[j + 1] = key;
    }
    for (int i = 0; i < d; i++) csr_src[s0 + i] = buf[i];
}

// ---------------- bf16 MFMA GEMM, single-matrix 32-row tile (R11 form) ----------------
template<bool LN, bool OUTF, bool EMB>
__global__ __launch_bounds__(256) void gemm_mfma(
    const u16* __restrict__ Abf, const u16* __restrict__ A2bf,
    const float* __restrict__ Aln, const float* __restrict__ lnacc,
    const float* __restrict__ lng, const float* __restrict__ lnb,
    const int* __restrict__ xidx, const float* __restrict__ emb, u16* __restrict__ h_out,
    const u16* __restrict__ Wt1, const float* __restrict__ b1,
    float* __restrict__ C1f, u16* __restrict__ C1h,
    const u16* __restrict__ Wt2, const float* __restrict__ b2, u16* __restrict__ C2h,
    float* __restrict__ bnacc, int M)
{
    __shared__ u16 As[32 * 136];     // padded row stride 136 -> only free 2-way conflicts
    __shared__ float sLN[2];
    const u16*  Wt   = blockIdx.y ? Wt2 : Wt1;
    const float* bias = blockIdx.y ? b2 : b1;
    u16*        Ch   = blockIdx.y ? C2h : C1h;
    int t = threadIdx.x;
    int m0 = blockIdx.x * 32;
    int lane = t & 63, w = t >> 6;
    int n16 = lane & 15, quad = lane >> 4;
    int c0 = w * 32;

    bfrag bW[2][4];
    #pragma unroll
    for (int c = 0; c < 2; c++)
        #pragma unroll
        for (int ks = 0; ks < 4; ks++)
            bW[c][ks] = *(const bfrag*)(Wt + (size_t)(c0 + c * 16 + n16) * 128 + ks * 32 + quad * 8);

    if (LN) {
        if (w == 0) {   // wave 0: reduce the 64 (sum,sumsq) partial slots
            float2 v = ((const float2*)lnacc)[lane];
            float s = v.x, ss = v.y;
            #pragma unroll
            for (int off = 32; off > 0; off >>= 1) {
                s += __shfl_xor(s, off); ss += __shfl_xor(ss, off);
            }
            if (lane == 0) {
                const float invM = 1.f / ((float)N_NODES * (float)D);
                float mu  = s * invM;
                float var = ss * invM - mu * mu;
                sLN[0] = mu;
                sLN[1] = rsqrtf(var + LN_EPS);
            }
        }
        __syncthreads();
        float mu = sLN[0], inv = sLN[1];
        #pragma unroll
        for (int i = 0; i < 4; i++) {
            int idx = t + 256 * i;           // 1024 float4 chunks
            int row = idx >> 5, c4 = idx & 31;
            int gr = m0 + row;
            float4 v = make_float4(0.f, 0.f, 0.f, 0.f);
            if (gr < M) v = ((const float4*)(Aln + (size_t)gr * D))[c4];
            float4 gv = ((const float4*)lng)[c4];
            float4 bv = ((const float4*)lnb)[c4];
            v.x = (v.x - mu) * inv * gv.x + bv.x; v.x = v.x > 0.f ? v.x : 0.f;
            v.y = (v.y - mu) * inv * gv.y + bv.y; v.y = v.y > 0.f ? v.y : 0.f;
            v.z = (v.z - mu) * inv * gv.z + bv.z; v.z = v.z > 0.f ? v.z : 0.f;
            v.w = (v.w - mu) * inv * gv.w + bv.w; v.w = v.w > 0.f ? v.w : 0.f;
            uint2 pk = make_uint2(pack2(v.x, v.y), pack2(v.z, v.w));
            *(uint2*)&As[row * 136 + c4 * 4] = pk;
        }
    } else if (EMB) {
        #pragma unroll
        for (int i = 0; i < 2; i++) {
            int idx = t + 256 * i;           // 512 chunks of 16B (8 bf16)
            int row = idx >> 4, c16 = idx & 15;
            int gr = m0 + row;
            uint4 v = make_uint4(0u, 0u, 0u, 0u);
            if (gr < M) {
                const float* er = emb + (size_t)xidx[gr] * D + c16 * 8;
                float4 e0 = ((const float4*)er)[0];
                float4 e1 = ((const float4*)er)[1];
                v.x = pack2(e0.x, e0.y); v.y = pack2(e0.z, e0.w);
                v.z = pack2(e1.x, e1.y); v.w = pack2(e1.z, e1.w);
                if (blockIdx.y == 0)      // persist h once for the final GEMM
                    ((uint4*)(h_out + (size_t)gr * 128))[c16] = v;
            }
            *(uint4*)&As[row * 136 + c16 * 8] = v;
        }
    } else {
        #pragma unroll
        for (int i = 0; i < 2; i++) {
            int idx = t + 256 * i;           // 512 chunks of 16B
            int row = idx >> 4, c16 = idx & 15;
            int gr = m0 + row;
            uint4 v = make_uint4(0u, 0u, 0u, 0u);
            if (gr < M) {
                v = ((const uint4*)(Abf + (size_t)gr * 128))[c16];
                if (A2bf) {
                    uint4 u = ((const uint4*)(A2bf + (size_t)gr * 128))[c16];
                    v.x = bfadd2(v.x, u.x); v.y = bfadd2(v.y, u.y);
                    v.z = bfadd2(v.z, u.z); v.w = bfadd2(v.w, u.w);
                }
            }
            *(uint4*)&As[row * 136 + c16 * 8] = v;
        }
    }
    __syncthreads();

    f32x4 zero = {0.f, 0.f, 0.f, 0.f};
    f32x4 acc[2][2] = {{zero, zero}, {zero, zero}};
    #pragma unroll
    for (int ks = 0; ks < 4; ks++) {
        bfrag a[2];
        #pragma unroll
        for (int r = 0; r < 2; r++)
            a[r] = *(const bfrag*)&As[(r * 16 + n16) * 136 + ks * 32 + quad * 8];
        #pragma unroll
        for (int r = 0; r < 2; r++)
            #pragma unroll
            for (int c = 0; c < 2; c++)
                acc[r][c] = __builtin_amdgcn_mfma_f32_16x16x32_bf16(a[r], bW[c][ks], acc[r][c], 0, 0, 0);
    }

    float bv[2] = { bias[c0 + n16], bias[c0 + 16 + n16] };
    float bns[2] = {0.f, 0.f}, bnss[2] = {0.f, 0.f};
    #pragma unroll
    for (int r = 0; r < 2; r++)
        #pragma unroll
        for (int c = 0; c < 2; c++)
            #pragma unroll
            for (int reg = 0; reg < 4; reg++) {
                int grow = m0 + r * 16 + quad * 4 + reg;
                if (grow < M) {
                    float val = acc[r][c][reg] + bv[c];
                    int col = c0 + c * 16 + n16;
                    if (OUTF) {
                        C1f[(size_t)grow * 128 + col] = val;
                        bns[c] += val; bnss[c] += val * val;
                    } else {
                        Ch[(size_t)grow * 128 + col] = f2bf(val);
                    }
                }
            }
    if (OUTF) {
        // reduce per-column partials over quads (rows), then 16-slot spread atomics
        #pragma unroll
        for (int c = 0; c < 2; c++) {
            #pragma unroll
            for (int msk = 16; msk <= 32; msk <<= 1) {
                bns[c]  += __shfl_xor(bns[c], msk);
                bnss[c] += __shfl_xor(bnss[c], msk);
            }
        }
        if (quad == 0) {
            float* base = bnacc + (size_t)(blockIdx.x & 15) * 256;
            #pragma unroll
            for (int c = 0; c < 2; c++) {
                int col = c0 + c * 16 + n16;
                atomicAdd(&base[col], bns[c]);
                atomicAdd(&base[128 + col], bnss[c]);
            }
        }
    }
}

// ---------------- GATv2 edge phase (R8 form + R12 locality) ----------------
// Commutative no-max softmax; 16-lane group per edge, 4 in flight; DPP score reduce.
// csr_src sorted ascending per node => sweeping src window (L2-resident).
// xr read and output stores use non-temporal hints (native ext-vector types)
// to avoid evicting xl from L2.
__global__ __launch_bounds__(256) void gat_agg(
    const u16* __restrict__ xl, const u16* __restrict__ xr,
    const int* __restrict__ row_off, const int* __restrict__ csr_src,
    const float* __restrict__ att, const float* __restrict__ conv_bias,
    float* __restrict__ xg, u16* __restrict__ xg_bf, float* __restrict__ lnacc)
{
    int wave = threadIdx.x >> 6, lane = threadIdx.x & 63;
    int node = blockIdx.x * 4 + wave;          // 7500*4 == 30000 exactly
    int g = lane >> 4, q = lane & 15;

    u32x4 rr = __builtin_nontemporal_load((const u32x4*)(xr + (size_t)node * 128) + q);
    float4 r0 = make_float4(bflo(rr.x), bfhi(rr.x), bflo(rr.y), bfhi(rr.y));
    float4 r1 = make_float4(bflo(rr.z), bfhi(rr.z), bflo(rr.w), bfhi(rr.w));
    float4 av0 = ((const float4*)att)[2 * q];
    float4 av1 = ((const float4*)att)[2 * q + 1];

    int s0 = row_off[node], s1 = row_off[node + 1];
    float denom = 0.f;
    float4 a0 = make_float4(0.f, 0.f, 0.f, 0.f), a1 = a0;

    #pragma unroll 4
    for (int s = s0 + g; s < s1; s += 4) {
        int src = csr_src[s];
        uint4 raw = *(const uint4*)(xl + (size_t)src * 128 + q * 8);
        float4 v0 = make_float4(bflo(raw.x), bfhi(raw.x), bflo(raw.y), bfhi(raw.y));
        float4 v1 = make_float4(bflo(raw.z), bfhi(raw.z), bflo(raw.w), bfhi(raw.w));
        float pr = 0.f, tt;
        tt = v0.x + r0.x; tt = tt > 0.f ? tt : NEG_SLOPE * tt; pr += av0.x * tt;
        tt = v0.y + r0.y; tt = tt > 0.f ? tt : NEG_SLOPE * tt; pr += av0.y * tt;
        tt = v0.z + r0.z; tt = tt > 0.f ? tt : NEG_SLOPE * tt; pr += av0.z * tt;
        tt = v0.w + r0.w; tt = tt > 0.f ? tt : NEG_SLOPE * tt; pr += av0.w * tt;
        tt = v1.x + r1.x; tt = tt > 0.f ? tt : NEG_SLOPE * tt; pr += av1.x * tt;
        tt = v1.y + r1.y; tt = tt > 0.f ? tt : NEG_SLOPE * tt; pr += av1.y * tt;
        tt = v1.z + r1.z; tt = tt > 0.f ? tt : NEG_SLOPE * tt; pr += av1.z * tt;
        tt = v1.w + r1.w; tt = tt > 0.f ? tt : NEG_SLOPE * tt; pr += av1.w * tt;
        pr = red16_dpp(pr);                     // 16-lane sum at VALU speed
        float wv = __expf(pr);
        denom += wv;
        a0.x += wv * v0.x; a0.y += wv * v0.y; a0.z += wv * v0.z; a0.w += wv * v0.w;
        a1.x += wv * v1.x; a1.y += wv * v1.y; a1.z += wv * v1.z; a1.w += wv * v1.w;
    }

    // merge the 4 groups (all commutative sums)
    #pragma unroll
    for (int msk = 16; msk <= 32; msk <<= 1) {
        denom += __shfl_xor(denom, msk);
        a0.x += __shfl_xor(a0.x, msk); a0.y += __shfl_xor(a0.y, msk);
        a0.z += __shfl_xor(a0.z, msk); a0.w += __shfl_xor(a0.w, msk);
        a1.x += __shfl_xor(a1.x, msk); a1.y += __shfl_xor(a1.y, msk);
        a1.z += __shfl_xor(a1.z, msk); a1.w += __shfl_xor(a1.w, msk);
    }

    float4 cb0 = ((const float4*)conv_bias)[2 * q];
    float4 cb1 = ((const float4*)conv_bias)[2 * q + 1];
    float inv = 1.f / denom;
    float4 o0, o1;
    o0.x = a0.x * inv + cb0.x; o0.y = a0.y * inv + cb0.y;
    o0.z = a0.z * inv + cb0.z; o0.w = a0.w * inv + cb0.w;
    o1.x = a1.x * inv + cb1.x; o1.y = a1.y * inv + cb1.y;
    o1.z = a1.z * inv + cb1.z; o1.w = a1.w * inv + cb1.w;

    if (xg_bf) {                 // last layer: bf16 only (feeds final MFMA GEMM)
        if (g == 0) {
            u32x4 pk = { pack2(o0.x, o0.y), pack2(o0.z, o0.w),
                         pack2(o1.x, o1.y), pack2(o1.z, o1.w) };
            __builtin_nontemporal_store(pk, (u32x4*)(xg_bf + (size_t)node * 128) + q);
        }
    } else {                     // layers 0..4: fp32 (LN applied by next gemm) + LN stats
        if (g == 0) {
            f32x4 w0 = { o0.x, o0.y, o0.z, o0.w };
            f32x4 w1 = { o1.x, o1.y, o1.z, o1.w };
            __builtin_nontemporal_store(w0, (f32x4*)(xg + (size_t)node * 128) + 2 * q);
            __builtin_nontemporal_store(w1, (f32x4*)(xg + (size_t)node * 128) + 2 * q + 1);
        }
        float s  = o0.x + o0.y + o0.z + o0.w + o1.x + o1.y + o1.z + o1.w;
        float ss = o0.x*o0.x + o0.y*o0.y + o0.z*o0.z + o0.w*o0.w
                 + o1.x*o1.x + o1.y*o1.y + o1.z*o1.z + o1.w*o1.w;
        s  = red16_dpp(s);
        ss = red16_dpp(ss);
        __shared__ float sred[8];
        if (lane == 0) { sred[wave] = s; sred[4 + wave] = ss; }
        __syncthreads();
        if (threadIdx.x == 0) {
            int slot = blockIdx.x & 63;   // 64-slot spread vs same-address serialization
            atomicAdd(&lnacc[2 * slot],     sred[0] + sred[1] + sred[2] + sred[3]);
            atomicAdd(&lnacc[2 * slot + 1], sred[4] + sred[5] + sred[6] + sred[7]);
        }
    }
}

// ---------------- BatchNorm1d apply (stats pre-accumulated by final GEMM) ----------------
__global__ __launch_bounds__(256) void bn_apply(float* __restrict__ out, const float* __restrict__ acc,
        const float* __restrict__ g, const float* __restrict__ b)
{
    int idx = blockIdx.x * 256 + threadIdx.x;
    if (idx >= N_NODES * 32) return;
    int c4 = idx & 31;
    float4 s1 = make_float4(0.f, 0.f, 0.f, 0.f), s2 = s1;
    #pragma unroll
    for (int slot = 0; slot < 16; slot++) {
        float4 a = ((const float4*)(acc + slot * 256))[c4];
        float4 d = ((const float4*)(acc + slot * 256 + 128))[c4];
        s1.x += a.x; s1.y += a.y; s1.z += a.z; s1.w += a.w;
        s2.x += d.x; s2.y += d.y; s2.z += d.z; s2.w += d.w;
    }
    float4 gv = ((const float4*)g)[c4];
    float4 bv = ((const float4*)b)[c4];
    float4 v = ((float4*)out)[idx];
    const float invN = 1.f / (float)N_NODES;
    float mu, var, inv;
    mu = s1.x * invN; var = s2.x * invN - mu * mu; inv = rsqrtf(var + LN_EPS);
    v.x = (v.x - mu) * inv * gv.x + bv.x;
    mu = s1.y * invN; var = s2.y * invN - mu * mu; inv = rsqrtf(var + LN_EPS);
    v.y = (v.y - mu) * inv * gv.y + bv.y;
    mu = s1.z * invN; var = s2.z * invN - mu * mu; inv = rsqrtf(var + LN_EPS);
    v.z = (v.z - mu) * inv * gv.z + bv.z;
    mu = s1.w * invN; var = s2.w * invN - mu * mu; inv = rsqrtf(var + LN_EPS);
    v.w = (v.w - mu) * inv * gv.w + bv.w;
    ((float4*)out)[idx] = v;
}

extern "C" void kernel_launch(void* const* d_in, const int* in_sizes, int n_in,
                              void* d_out, int out_size, void* d_ws, size_t ws_size,
                              hipStream_t stream)
{
    const int*   x    = (const int*)d_in[0];
    const int*   ei   = (const int*)d_in[1];
    const float* emb  = (const float*)d_in[2];
    const float* Wl   = (const float*)d_in[3];
    const float* bl   = (const float*)d_in[4];
    const float* Wr   = (const float*)d_in[5];
    const float* br   = (const float*)d_in[6];
    const float* att  = (const float*)d_in[7];
    const float* cbias= (const float*)d_in[8];
    const float* lng  = (const float*)d_in[9];
    const float* lnb  = (const float*)d_in[10];
    const float* linW = (const float*)d_in[11];
    const float* linb = (const float*)d_in[12];
    const float* bng  = (const float*)d_in[13];
    const float* bnb  = (const float*)d_in[14];
    float* out = (float*)d_out;

    char* p = (char*)d_ws;
    float* xg    = (float*)p; p += (size_t)N_NODES * D * 4;
    u16*   xl_bf = (u16*)p;   p += (size_t)N_NODES * D * 2;
    u16*   xr_bf = (u16*)p;   p += (size_t)N_NODES * D * 2;
    u16*   xg_bf = (u16*)p;   p += (size_t)N_NODES * D * 2;
    u16*   h_bf  = (u16*)p;   p += (size_t)N_NODES * D * 2;
    u16*   wt    = (u16*)p;   p += (size_t)13 * 16384 * 2;
    int* cnt     = (int*)p; p += ((N_NODES * 4 + 255) / 256) * 256;
    int* lscan   = (int*)p; p += ((N_NODES * 4 + 255) / 256) * 256;
    int* row_off = (int*)p; p += (((N_NODES + 1) * 4 + 255) / 256) * 256;
    int* cursor  = (int*)p; p += ((N_NODES * 4 + 255) / 256) * 256;
    int* csr_src = (int*)p; p += ((E2 * 4 + 255) / 256) * 256;
    int* bsum    = (int*)p; p += 256;
    float* accs  = (float*)p; p += 20480;
    // accs layout (floats): LN layer i partials at [i*128 .. i*128+128) as 64x float2 (i<5);
    // BN 16-slot column stats at [640 .. 640+4096)

    hipMemsetAsync(cnt, 0, N_NODES * 4, stream);
    hipMemsetAsync(accs, 0, (640 + 4096) * 4, stream);

    wt_convert<<<13, 256, 0, stream>>>(Wl, Wr, linW, wt);
    hist_kernel<<<(E2 + 255) / 256, 256, 0, stream>>>(ei, cnt);
    scan1_kernel<<<30, 1024, 0, stream>>>(cnt, lscan, bsum);
    scan3_kernel<<<30, 1024, 0, stream>>>(lscan, bsum, cnt, row_off, cursor);
    scatter_kernel<<<(E2 + 255) / 256, 256, 0, stream>>>(ei, cursor, csr_src);
    sort_kernel<<<(N_NODES + 255) / 256, 256, 0, stream>>>(row_off, csr_src);

    const int GX = (N_NODES + 31) / 32;   // 938
    for (int i = 0; i < LAYERS; i++) {
        if (i == 0) {
            gemm_mfma<false, false, true><<<dim3(GX, 2), 256, 0, stream>>>(
                nullptr, nullptr, nullptr, nullptr, nullptr, nullptr,
                x, emb, h_bf,
                wt + (size_t)0 * 16384, bl + 0, nullptr, xl_bf,
                wt + (size_t)1 * 16384, br + 0, xr_bf, nullptr, N_NODES);
        } else {
            gemm_mfma<true, false, false><<<dim3(GX, 2), 256, 0, stream>>>(
                nullptr, nullptr, xg, accs + (i - 1) * 128,
                lng + (size_t)(i - 1) * D, lnb + (size_t)(i - 1) * D,
                nullptr, nullptr, nullptr,
                wt + (size_t)(2 * i) * 16384, bl + i * D, nullptr, xl_bf,
                wt + (size_t)(2 * i + 1) * 16384, br + i * D, xr_bf, nullptr, N_NODES);
        }
        gat_agg<<<7500, 256, 0, stream>>>(xl_bf, xr_bf, row_off, csr_src,
            att + i * D, cbias + i * D, xg,
            (i == LAYERS - 1) ? xg_bf : nullptr,
            (i < LAYERS - 1) ? (accs + i * 128) : nullptr);
    }
    gemm_mfma<false, true, false><<<dim3(GX, 1), 256, 0, stream>>>(
        xg_bf, h_bf, nullptr, nullptr, nullptr, nullptr,
        nullptr, nullptr, nullptr,
        wt + (size_t)12 * 16384, linb, out, nullptr,
        nullptr, nullptr, nullptr, accs + 640, N_NODES);
    bn_apply<<<3750, 256, 0, stream>>>(out, accs + 640, bng, bnb);
}

// Round 14
// 570.346 us; speedup vs baseline: 1.0109x; 1.0109x over previous
//
#include <hip/hip_runtime.h>
#include <math.h>

#define N_NODES 30000
#define N_EDGES 240000
#define E2 (N_EDGES + N_NODES)   // 270000 with self-loops
#define D 128
#define LAYERS 6
#define NEG_SLOPE 0.2f
#define LN_EPS 1e-5f

typedef unsigned short u16;
typedef unsigned int u32;
using bfrag = __attribute__((ext_vector_type(8))) short;
using f32x4 = __attribute__((ext_vector_type(4))) float;

__device__ inline u16 f2bf(float f) {
    u32 u = __float_as_uint(f);
    u32 r = u + 0x7fffu + ((u >> 16) & 1u);
    return (u16)(r >> 16);
}
__device__ inline u32 pack2(float a, float b) { return (u32)f2bf(a) | ((u32)f2bf(b) << 16); }
__device__ inline float bflo(u32 u) { return __uint_as_float(u << 16); }
__device__ inline float bfhi(u32 u) { return __uint_as_float(u & 0xffff0000u); }
__device__ inline u32 bfadd2(u32 a, u32 b) {
    return pack2(bflo(a) + bflo(b), bfhi(a) + bfhi(b));
}

// 16-lane sum reduce via DPP (VALU-speed): xor1 (0xB1), xor2 (0x4E),
// row_half_mirror (0x141), row_mirror (0x140).
__device__ inline float red16_dpp(float x) {
    x += __int_as_float(__builtin_amdgcn_update_dpp(0, __float_as_int(x), 0xB1, 0xF, 0xF, true));
    x += __int_as_float(__builtin_amdgcn_update_dpp(0, __float_as_int(x), 0x4E, 0xF, 0xF, true));
    x += __int_as_float(__builtin_amdgcn_update_dpp(0, __float_as_int(x), 0x141, 0xF, 0xF, true));
    x += __int_as_float(__builtin_amdgcn_update_dpp(0, __float_as_int(x), 0x140, 0xF, 0xF, true));
    return x;
}
// 64-lane sum: DPP row sums + scalar-path cross-row combine (no LDS-pipe ops)
__device__ inline float red64_dpp(float x) {
    x = red16_dpp(x);
    float a = __int_as_float(__builtin_amdgcn_readlane(__float_as_int(x), 0));
    float b = __int_as_float(__builtin_amdgcn_readlane(__float_as_int(x), 16));
    float c = __int_as_float(__builtin_amdgcn_readlane(__float_as_int(x), 32));
    float d = __int_as_float(__builtin_amdgcn_readlane(__float_as_int(x), 48));
    return (a + b) + (c + d);    // wave-uniform
}

// ---------------- weight prep: Wt[b][n][k] = bf16(W[b][k][n]) ----------------
__global__ __launch_bounds__(256) void wt_convert(const float* __restrict__ Wl,
        const float* __restrict__ Wr, const float* __restrict__ linW, u16* __restrict__ wt)
{
    __shared__ u16 tile[128 * 129];
    int b = blockIdx.x;
    const float* src = (b == 12) ? linW
                     : ((b & 1) ? Wr + (size_t)(b >> 1) * 16384 : Wl + (size_t)(b >> 1) * 16384);
    int t = threadIdx.x;
    #pragma unroll 4
    for (int i = 0; i < 64; i++) {
        int idx = t + 256 * i;           // idx = k*128 + n
        int k = idx >> 7, n = idx & 127;
        tile[n * 129 + k] = f2bf(src[idx]);
    }
    __syncthreads();
    u16* dst = wt + (size_t)b * 16384;
    #pragma unroll 4
    for (int i = 0; i < 64; i++) {
        int idx = t + 256 * i;           // idx = n*128 + k
        int n = idx >> 7, k = idx & 127;
        dst[idx] = tile[n * 129 + k];
    }
}

// ---------------- CSR build (by dst) ----------------
__global__ __launch_bounds__(256) void hist_kernel(const int* __restrict__ ei, int* __restrict__ cnt)
{
    int e = blockIdx.x * 256 + threadIdx.x;
    if (e >= E2) return;
    int d = (e < N_EDGES) ? ei[N_EDGES + e] : (e - N_EDGES);
    atomicAdd(&cnt[d], 1);
}

__global__ __launch_bounds__(1024) void scan1_kernel(const int* __restrict__ cnt,
        int* __restrict__ lscan, int* __restrict__ bsum)
{
    __shared__ int wtot[16];
    int t = threadIdx.x, lane = t & 63, w = t >> 6;
    int i = blockIdx.x * 1024 + t;
    int v = (i < N_NODES) ? cnt[i] : 0;
    int s = v;
    #pragma unroll
    for (int off = 1; off < 64; off <<= 1) {
        int u = __shfl_up(s, off);
        if (lane >= off) s += u;
    }
    if (lane == 63) wtot[w] = s;
    __syncthreads();
    if (t < 16) {
        int xv = wtot[t];
        #pragma unroll
        for (int off = 1; off < 16; off <<= 1) {
            int u = __shfl_up(xv, off);
            if (t >= off) xv += u;
        }
        wtot[t] = xv;
    }
    __syncthreads();
    int incl = ((w == 0) ? 0 : wtot[w - 1]) + s;
    if (i < N_NODES) lscan[i] = incl;
    if (t == 0) bsum[blockIdx.x] = wtot[15];
}

// scan3 with integrated 30-element block-offset scan
__global__ __launch_bounds__(1024) void scan3_kernel(const int* __restrict__ lscan,
        const int* __restrict__ bsum, const int* __restrict__ cnt,
        int* __restrict__ row_off, int* __restrict__ cursor)
{
    __shared__ int sboff;
    if (threadIdx.x < 64) {
        int v = (threadIdx.x < 30) ? bsum[threadIdx.x] : 0;
        int s = v;
        #pragma unroll
        for (int off = 1; off < 64; off <<= 1) {
            int u = __shfl_up(s, off);
            if ((int)threadIdx.x >= off) s += u;
        }
        if (threadIdx.x == blockIdx.x) sboff = s - v;   // exclusive prefix
    }
    __syncthreads();
    int i = blockIdx.x * 1024 + threadIdx.x;
    if (i == 0) row_off[0] = 0;
    if (i < N_NODES) {
        int r = lscan[i] + sboff;
        row_off[i + 1] = r;
        cursor[i] = r - cnt[i];
    }
}

__global__ __launch_bounds__(256) void scatter_kernel(const int* __restrict__ ei,
        int* __restrict__ cursor, int* __restrict__ csr_src)
{
    int e = blockIdx.x * 256 + threadIdx.x;
    if (e >= E2) return;
    int s, d;
    if (e < N_EDGES) { s = ei[e]; d = ei[N_EDGES + e]; }
    else             { s = e - N_EDGES; d = s; }
    int pos = atomicAdd(&cursor[d], 1);
    csr_src[pos] = s;
}

// ---------------- bf16 MFMA GEMM, single-matrix 32-row tile (R11 form) ----------------
template<bool LN, bool OUTF, bool EMB>
__global__ __launch_bounds__(256) void gemm_mfma(
    const u16* __restrict__ Abf, const u16* __restrict__ A2bf,
    const float* __restrict__ Aln, const float* __restrict__ lnacc,
    const float* __restrict__ lng, const float* __restrict__ lnb,
    const int* __restrict__ xidx, const float* __restrict__ emb, u16* __restrict__ h_out,
    const u16* __restrict__ Wt1, const float* __restrict__ b1,
    float* __restrict__ C1f, u16* __restrict__ C1h,
    const u16* __restrict__ Wt2, const float* __restrict__ b2, u16* __restrict__ C2h,
    float* __restrict__ bnacc, int M)
{
    __shared__ u16 As[32 * 136];     // padded row stride 136 -> only free 2-way conflicts
    __shared__ float sLN[2];
    const u16*  Wt   = blockIdx.y ? Wt2 : Wt1;
    const float* bias = blockIdx.y ? b2 : b1;
    u16*        Ch   = blockIdx.y ? C2h : C1h;
    int t = threadIdx.x;
    int m0 = blockIdx.x * 32;
    int lane = t & 63, w = t >> 6;
    int n16 = lane & 15, quad = lane >> 4;
    int c0 = w * 32;

    bfrag bW[2][4];
    #pragma unroll
    for (int c = 0; c < 2; c++)
        #pragma unroll
        for (int ks = 0; ks < 4; ks++)
            bW[c][ks] = *(const bfrag*)(Wt + (size_t)(c0 + c * 16 + n16) * 128 + ks * 32 + quad * 8);

    if (LN) {
        if (w == 0) {   // wave 0: reduce the 64 (sum,sumsq) partial slots
            float2 v = ((const float2*)lnacc)[lane];
            float s = v.x, ss = v.y;
            #pragma unroll
            for (int off = 32; off > 0; off >>= 1) {
                s += __shfl_xor(s, off); ss += __shfl_xor(ss, off);
            }
            if (lane == 0) {
                const float invM = 1.f / ((float)N_NODES * (float)D);
                float mu  = s * invM;
                float var = ss * invM - mu * mu;
                sLN[0] = mu;
                sLN[1] = rsqrtf(var + LN_EPS);
            }
        }
        __syncthreads();
        float mu = sLN[0], inv = sLN[1];
        #pragma unroll
        for (int i = 0; i < 4; i++) {
            int idx = t + 256 * i;           // 1024 float4 chunks
            int row = idx >> 5, c4 = idx & 31;
            int gr = m0 + row;
            float4 v = make_float4(0.f, 0.f, 0.f, 0.f);
            if (gr < M) v = ((const float4*)(Aln + (size_t)gr * D))[c4];
            float4 gv = ((const float4*)lng)[c4];
            float4 bv = ((const float4*)lnb)[c4];
            v.x = (v.x - mu) * inv * gv.x + bv.x; v.x = v.x > 0.f ? v.x : 0.f;
            v.y = (v.y - mu) * inv * gv.y + bv.y; v.y = v.y > 0.f ? v.y : 0.f;
            v.z = (v.z - mu) * inv * gv.z + bv.z; v.z = v.z > 0.f ? v.z : 0.f;
            v.w = (v.w - mu) * inv * gv.w + bv.w; v.w = v.w > 0.f ? v.w : 0.f;
            uint2 pk = make_uint2(pack2(v.x, v.y), pack2(v.z, v.w));
            *(uint2*)&As[row * 136 + c4 * 4] = pk;
        }
    } else if (EMB) {
        #pragma unroll
        for (int i = 0; i < 2; i++) {
            int idx = t + 256 * i;           // 512 chunks of 16B (8 bf16)
            int row = idx >> 4, c16 = idx & 15;
            int gr = m0 + row;
            uint4 v = make_uint4(0u, 0u, 0u, 0u);
            if (gr < M) {
                const float* er = emb + (size_t)xidx[gr] * D + c16 * 8;
                float4 e0 = ((const float4*)er)[0];
                float4 e1 = ((const float4*)er)[1];
                v.x = pack2(e0.x, e0.y); v.y = pack2(e0.z, e0.w);
                v.z = pack2(e1.x, e1.y); v.w = pack2(e1.z, e1.w);
                if (blockIdx.y == 0)      // persist h once for the final GEMM
                    ((uint4*)(h_out + (size_t)gr * 128))[c16] = v;
            }
            *(uint4*)&As[row * 136 + c16 * 8] = v;
        }
    } else {
        #pragma unroll
        for (int i = 0; i < 2; i++) {
            int idx = t + 256 * i;           // 512 chunks of 16B
            int row = idx >> 4, c16 = idx & 15;
            int gr = m0 + row;
            uint4 v = make_uint4(0u, 0u, 0u, 0u);
            if (gr < M) {
                v = ((const uint4*)(Abf + (size_t)gr * 128))[c16];
                if (A2bf) {
                    uint4 u = ((const uint4*)(A2bf + (size_t)gr * 128))[c16];
                    v.x = bfadd2(v.x, u.x); v.y = bfadd2(v.y, u.y);
                    v.z = bfadd2(v.z, u.z); v.w = bfadd2(v.w, u.w);
                }
            }
            *(uint4*)&As[row * 136 + c16 * 8] = v;
        }
    }
    __syncthreads();

    f32x4 zero = {0.f, 0.f, 0.f, 0.f};
    f32x4 acc[2][2] = {{zero, zero}, {zero, zero}};
    #pragma unroll
    for (int ks = 0; ks < 4; ks++) {
        bfrag a[2];
        #pragma unroll
        for (int r = 0; r < 2; r++)
            a[r] = *(const bfrag*)&As[(r * 16 + n16) * 136 + ks * 32 + quad * 8];
        #pragma unroll
        for (int r = 0; r < 2; r++)
            #pragma unroll
            for (int c = 0; c < 2; c++)
                acc[r][c] = __builtin_amdgcn_mfma_f32_16x16x32_bf16(a[r], bW[c][ks], acc[r][c], 0, 0, 0);
    }

    float bv[2] = { bias[c0 + n16], bias[c0 + 16 + n16] };
    float bns[2] = {0.f, 0.f}, bnss[2] = {0.f, 0.f};
    #pragma unroll
    for (int r = 0; r < 2; r++)
        #pragma unroll
        for (int c = 0; c < 2; c++)
            #pragma unroll
            for (int reg = 0; reg < 4; reg++) {
                int grow = m0 + r * 16 + quad * 4 + reg;
                if (grow < M) {
                    float val = acc[r][c][reg] + bv[c];
                    int col = c0 + c * 16 + n16;
                    if (OUTF) {
                        C1f[(size_t)grow * 128 + col] = val;
                        bns[c] += val; bnss[c] += val * val;
                    } else {
                        Ch[(size_t)grow * 128 + col] = f2bf(val);
                    }
                }
            }
    if (OUTF) {
        // reduce per-column partials over quads (rows), then 16-slot spread atomics
        #pragma unroll
        for (int c = 0; c < 2; c++) {
            #pragma unroll
            for (int msk = 16; msk <= 32; msk <<= 1) {
                bns[c]  += __shfl_xor(bns[c], msk);
                bnss[c] += __shfl_xor(bnss[c], msk);
            }
        }
        if (quad == 0) {
            float* base = bnacc + (size_t)(blockIdx.x & 15) * 256;
            #pragma unroll
            for (int c = 0; c < 2; c++) {
                int col = c0 + c * 16 + n16;
                atomicAdd(&base[col], bns[c]);
                atomicAdd(&base[128 + col], bnss[c]);
            }
        }
    }
}

// ---------------- GATv2 edge phase (R14): one ROW per wave instruction ----------------
// Lane c owns channels 2c,2c+1 (u32 of bf16x2); a row gather = 64 lanes x 4B =
// 256B = 4 CONTIGUOUS cache lines per instruction (vs 16 scattered in R8 form,
// which pinned every prior variant at ~52us on TA line-processing).
// MLP via 12-deep register row buffer; addresses via scalar path (readlane+sALU).
// Per-edge reduce: 4 DPP + 4 readlane + 3 VALU adds (no LDS-pipe ops).
// Commutative no-max softmax (scores O(1), fp32 exp safe). No cross-lane acc merge.
__global__ __launch_bounds__(256) void gat_agg(
    const u16* __restrict__ xl, const u16* __restrict__ xr,
    const int* __restrict__ row_off, const int* __restrict__ csr_src,
    const float* __restrict__ att, const float* __restrict__ conv_bias,
    float* __restrict__ xg, u16* __restrict__ xg_bf, float* __restrict__ lnacc)
{
    int wave = threadIdx.x >> 6, lane = threadIdx.x & 63;
    int node = blockIdx.x * 4 + wave;          // 7500*4 == 30000 exactly

    u32 rr = ((const u32*)(xr + (size_t)node * 128))[lane];
    float rlo = bflo(rr), rhi = bfhi(rr);
    float2 av = ((const float2*)att)[lane];
    float2 cb = ((const float2*)conv_bias)[lane];

    int s0 = row_off[node], s1 = row_off[node + 1];
    float denom = 0.f, alo = 0.f, ahi = 0.f;

    for (int cs = s0; cs < s1; cs += 12) {
        int cnt = s1 - cs; cnt = cnt < 12 ? cnt : 12;
        // coalesced chunk of edge indices (lanes >= cnt load a dummy)
        int csrv = csr_src[(lane < cnt) ? (cs + lane) : cs];
        u32 vbuf[12];
        #pragma unroll
        for (int j = 0; j < 12; j++) {        // issue contiguous row gathers back-to-back
            if (j >= cnt) break;
            int src = __builtin_amdgcn_readlane(csrv, j);
            vbuf[j] = ((const u32*)(xl + (size_t)src * 128))[lane];
        }
        #pragma unroll
        for (int j = 0; j < 12; j++) {
            if (j >= cnt) break;
            u32 v = vbuf[j];
            float vlo = bflo(v), vhi = bfhi(v);
            float tlo = vlo + rlo; tlo = tlo > 0.f ? tlo : NEG_SLOPE * tlo;
            float thi = vhi + rhi; thi = thi > 0.f ? thi : NEG_SLOPE * thi;
            float pr = av.x * tlo + av.y * thi;
            float wv = __expf(red64_dpp(pr));  // wave-uniform weight
            denom += wv;
            alo += wv * vlo;
            ahi += wv * vhi;
        }
    }

    float inv = 1.f / denom;
    float olo = alo * inv + cb.x;
    float ohi = ahi * inv + cb.y;

    if (xg_bf) {                 // last layer: bf16 only (feeds final MFMA GEMM)
        ((u32*)(xg_bf + (size_t)node * 128))[lane] = pack2(olo, ohi);
    } else {                     // layers 0..4: fp32 (LN applied by next gemm) + LN stats
        ((float2*)(xg + (size_t)node * 128))[lane] = make_float2(olo, ohi);
        float s  = red64_dpp(olo + ohi);
        float ss = red64_dpp(olo * olo + ohi * ohi);
        __shared__ float sred[8];
        if (lane == 0) { sred[wave] = s; sred[4 + wave] = ss; }
        __syncthreads();
        if (threadIdx.x == 0) {
            int slot = blockIdx.x & 63;   // 64-slot spread vs same-address serialization
            atomicAdd(&lnacc[2 * slot],     sred[0] + sred[1] + sred[2] + sred[3]);
            atomicAdd(&lnacc[2 * slot + 1], sred[4] + sred[5] + sred[6] + sred[7]);
        }
    }
}

// ---------------- BatchNorm1d apply (stats pre-accumulated by final GEMM) ----------------
__global__ __launch_bounds__(256) void bn_apply(float* __restrict__ out, const float* __restrict__ acc,
        const float* __restrict__ g, const float* __restrict__ b)
{
    int idx = blockIdx.x * 256 + threadIdx.x;
    if (idx >= N_NODES * 32) return;
    int c4 = idx & 31;
    float4 s1 = make_float4(0.f, 0.f, 0.f, 0.f), s2 = s1;
    #pragma unroll
    for (int slot = 0; slot < 16; slot++) {
        float4 a = ((const float4*)(acc + slot * 256))[c4];
        float4 d = ((const float4*)(acc + slot * 256 + 128))[c4];
        s1.x += a.x; s1.y += a.y; s1.z += a.z; s1.w += a.w;
        s2.x += d.x; s2.y += d.y; s2.z += d.z; s2.w += d.w;
    }
    float4 gv = ((const float4*)g)[c4];
    float4 bv = ((const float4*)b)[c4];
    float4 v = ((float4*)out)[idx];
    const float invN = 1.f / (float)N_NODES;
    float mu, var, inv;
    mu = s1.x * invN; var = s2.x * invN - mu * mu; inv = rsqrtf(var + LN_EPS);
    v.x = (v.x - mu) * inv * gv.x + bv.x;
    mu = s1.y * invN; var = s2.y * invN - mu * mu; inv = rsqrtf(var + LN_EPS);
    v.y = (v.y - mu) * inv * gv.y + bv.y;
    mu = s1.z * invN; var = s2.z * invN - mu * mu; inv = rsqrtf(var + LN_EPS);
    v.z = (v.z - mu) * inv * gv.z + bv.z;
    mu = s1.w * invN; var = s2.w * invN - mu * mu; inv = rsqrtf(var + LN_EPS);
    v.w = (v.w - mu) * inv * gv.w + bv.w;
    ((float4*)out)[idx] = v;
}

extern "C" void kernel_launch(void* const* d_in, const int* in_sizes, int n_in,
                              void* d_out, int out_size, void* d_ws, size_t ws_size,
                              hipStream_t stream)
{
    const int*   x    = (const int*)d_in[0];
    const int*   ei   = (const int*)d_in[1];
    const float* emb  = (const float*)d_in[2];
    const float* Wl   = (const float*)d_in[3];
    const float* bl   = (const float*)d_in[4];
    const float* Wr   = (const float*)d_in[5];
    const float* br   = (const float*)d_in[6];
    const float* att  = (const float*)d_in[7];
    const float* cbias= (const float*)d_in[8];
    const float* lng  = (const float*)d_in[9];
    const float* lnb  = (const float*)d_in[10];
    const float* linW = (const float*)d_in[11];
    const float* linb = (const float*)d_in[12];
    const float* bng  = (const float*)d_in[13];
    const float* bnb  = (const float*)d_in[14];
    float* out = (float*)d_out;

    char* p = (char*)d_ws;
    float* xg    = (float*)p; p += (size_t)N_NODES * D * 4;
    u16*   xl_bf = (u16*)p;   p += (size_t)N_NODES * D * 2;
    u16*   xr_bf = (u16*)p;   p += (size_t)N_NODES * D * 2;
    u16*   xg_bf = (u16*)p;   p += (size_t)N_NODES * D * 2;
    u16*   h_bf  = (u16*)p;   p += (size_t)N_NODES * D * 2;
    u16*   wt    = (u16*)p;   p += (size_t)13 * 16384 * 2;
    int* cnt     = (int*)p; p += ((N_NODES * 4 + 255) / 256) * 256;
    int* lscan   = (int*)p; p += ((N_NODES * 4 + 255) / 256) * 256;
    int* row_off = (int*)p; p += (((N_NODES + 1) * 4 + 255) / 256) * 256;
    int* cursor  = (int*)p; p += ((N_NODES * 4 + 255) / 256) * 256;
    int* csr_src = (int*)p; p += ((E2 * 4 + 255) / 256) * 256;
    int* bsum    = (int*)p; p += 256;
    float* accs  = (float*)p; p += 20480;
    // accs layout (floats): LN layer i partials at [i*128 .. i*128+128) as 64x float2 (i<5);
    // BN 16-slot column stats at [640 .. 640+4096)

    hipMemsetAsync(cnt, 0, N_NODES * 4, stream);
    hipMemsetAsync(accs, 0, (640 + 4096) * 4, stream);

    wt_convert<<<13, 256, 0, stream>>>(Wl, Wr, linW, wt);
    hist_kernel<<<(E2 + 255) / 256, 256, 0, stream>>>(ei, cnt);
    scan1_kernel<<<30, 1024, 0, stream>>>(cnt, lscan, bsum);
    scan3_kernel<<<30, 1024, 0, stream>>>(lscan, bsum, cnt, row_off, cursor);
    scatter_kernel<<<(E2 + 255) / 256, 256, 0, stream>>>(ei, cursor, csr_src);

    const int GX = (N_NODES + 31) / 32;   // 938
    for (int i = 0; i < LAYERS; i++) {
        if (i == 0) {
            gemm_mfma<false, false, true><<<dim3(GX, 2), 256, 0, stream>>>(
                nullptr, nullptr, nullptr, nullptr, nullptr, nullptr,
                x, emb, h_bf,
                wt + (size_t)0 * 16384, bl + 0, nullptr, xl_bf,
                wt + (size_t)1 * 16384, br + 0, xr_bf, nullptr, N_NODES);
        } else {
            gemm_mfma<true, false, false><<<dim3(GX, 2), 256, 0, stream>>>(
                nullptr, nullptr, xg, accs + (i - 1) * 128,
                lng + (size_t)(i - 1) * D, lnb + (size_t)(i - 1) * D,
                nullptr, nullptr, nullptr,
                wt + (size_t)(2 * i) * 16384, bl + i * D, nullptr, xl_bf,
                wt + (size_t)(2 * i + 1) * 16384, br + i * D, xr_bf, nullptr, N_NODES);
        }
        gat_agg<<<7500, 256, 0, stream>>>(xl_bf, xr_bf, row_off, csr_src,
            att + i * D, cbias + i * D, xg,
            (i == LAYERS - 1) ? xg_bf : nullptr,
            (i < LAYERS - 1) ? (accs + i * 128) : nullptr);
    }
    gemm_mfma<false, true, false><<<dim3(GX, 1), 256, 0, stream>>>(
        xg_bf, h_bf, nullptr, nullptr, nullptr, nullptr,
        nullptr, nullptr, nullptr,
        wt + (size_t)12 * 16384, linb, out, nullptr,
        nullptr, nullptr, nullptr, accs + 640, N_NODES);
    bn_apply<<<3750, 256, 0, stream>>>(out, accs + 640, bng, bnb);
}

// Round 15
// 509.543 us; speedup vs baseline: 1.1316x; 1.1193x over previous
//
#include <hip/hip_runtime.h>
#include <math.h>

#define N_NODES 30000
#define N_EDGES 240000
#define E2 (N_EDGES + N_NODES)   // 270000 with self-loops
#define D 128
#define LAYERS 6
#define NEG_SLOPE 0.2f
#define LN_EPS 1e-5f

typedef unsigned short u16;
typedef unsigned int u32;
using bfrag = __attribute__((ext_vector_type(8))) short;
using f32x4 = __attribute__((ext_vector_type(4))) float;
using u32x4 = __attribute__((ext_vector_type(4))) unsigned int;

__device__ inline u16 f2bf(float f) {
    u32 u = __float_as_uint(f);
    u32 r = u + 0x7fffu + ((u >> 16) & 1u);
    return (u16)(r >> 16);
}
__device__ inline u32 pack2(float a, float b) { return (u32)f2bf(a) | ((u32)f2bf(b) << 16); }
__device__ inline float bflo(u32 u) { return __uint_as_float(u << 16); }
__device__ inline float bfhi(u32 u) { return __uint_as_float(u & 0xffff0000u); }
__device__ inline u32 bfadd2(u32 a, u32 b) {
    return pack2(bflo(a) + bflo(b), bfhi(a) + bfhi(b));
}

// 16-lane sum reduce via DPP (VALU-speed): xor1 (0xB1), xor2 (0x4E),
// row_half_mirror (0x141), row_mirror (0x140).
__device__ inline float red16_dpp(float x) {
    x += __int_as_float(__builtin_amdgcn_update_dpp(0, __float_as_int(x), 0xB1, 0xF, 0xF, true));
    x += __int_as_float(__builtin_amdgcn_update_dpp(0, __float_as_int(x), 0x4E, 0xF, 0xF, true));
    x += __int_as_float(__builtin_amdgcn_update_dpp(0, __float_as_int(x), 0x141, 0xF, 0xF, true));
    x += __int_as_float(__builtin_amdgcn_update_dpp(0, __float_as_int(x), 0x140, 0xF, 0xF, true));
    return x;
}

// ---------------- weight prep (R15): FRAGMENT-ORDER layout ----------------
// dst element for (k,n): w=n>>5, c=(n>>4)&1, n16=n&15; ks=k>>5, quad=(k>>3)&3, e=k&7;
// lane=quad*16+n16; flat = (((w*2+c)*4+ks)*64 + lane)*8 + e.
// GEMM B-frag load becomes lane-consecutive 16B chunks (4 contiguous lines/instr
// instead of 16 scattered at 256B stride — same TA fix rationale as gat analysis).
__global__ __launch_bounds__(256) void wt_convert(const float* __restrict__ Wl,
        const float* __restrict__ Wr, const float* __restrict__ linW, u16* __restrict__ wt)
{
    __shared__ u16 frag[16384];
    int b = blockIdx.x;
    const float* src = (b == 12) ? linW
                     : ((b & 1) ? Wr + (size_t)(b >> 1) * 16384 : Wl + (size_t)(b >> 1) * 16384);
    int t = threadIdx.x;
    #pragma unroll 4
    for (int i = 0; i < 64; i++) {
        int idx = t + 256 * i;           // coalesced read: idx = k*128 + n
        int k = idx >> 7, n = idx & 127;
        int w = n >> 5, c = (n >> 4) & 1, n16 = n & 15;
        int ks = k >> 5, quad = (k >> 3) & 3, e = k & 7;
        int lane = quad * 16 + n16;
        frag[(((w * 2 + c) * 4 + ks) * 64 + lane) * 8 + e] = f2bf(src[idx]);
    }
    __syncthreads();
    u16* dst = wt + (size_t)b * 16384;
    #pragma unroll 4
    for (int i = 0; i < 64; i++) {
        int idx = t + 256 * i;
        dst[idx] = frag[idx];            // coalesced write
    }
}

// ---------------- CSR build (by dst) ----------------
__global__ __launch_bounds__(256) void hist_kernel(const int* __restrict__ ei, int* __restrict__ cnt)
{
    int e = blockIdx.x * 256 + threadIdx.x;
    if (e >= E2) return;
    int d = (e < N_EDGES) ? ei[N_EDGES + e] : (e - N_EDGES);
    atomicAdd(&cnt[d], 1);
}

__global__ __launch_bounds__(1024) void scan1_kernel(const int* __restrict__ cnt,
        int* __restrict__ lscan, int* __restrict__ bsum)
{
    __shared__ int wtot[16];
    int t = threadIdx.x, lane = t & 63, w = t >> 6;
    int i = blockIdx.x * 1024 + t;
    int v = (i < N_NODES) ? cnt[i] : 0;
    int s = v;
    #pragma unroll
    for (int off = 1; off < 64; off <<= 1) {
        int u = __shfl_up(s, off);
        if (lane >= off) s += u;
    }
    if (lane == 63) wtot[w] = s;
    __syncthreads();
    if (t < 16) {
        int xv = wtot[t];
        #pragma unroll
        for (int off = 1; off < 16; off <<= 1) {
            int u = __shfl_up(xv, off);
            if (t >= off) xv += u;
        }
        wtot[t] = xv;
    }
    __syncthreads();
    int incl = ((w == 0) ? 0 : wtot[w - 1]) + s;
    if (i < N_NODES) lscan[i] = incl;
    if (t == 0) bsum[blockIdx.x] = wtot[15];
}

// scan3 with integrated 30-element block-offset scan
__global__ __launch_bounds__(1024) void scan3_kernel(const int* __restrict__ lscan,
        const int* __restrict__ bsum, const int* __restrict__ cnt,
        int* __restrict__ row_off, int* __restrict__ cursor)
{
    __shared__ int sboff;
    if (threadIdx.x < 64) {
        int v = (threadIdx.x < 30) ? bsum[threadIdx.x] : 0;
        int s = v;
        #pragma unroll
        for (int off = 1; off < 64; off <<= 1) {
            int u = __shfl_up(s, off);
            if ((int)threadIdx.x >= off) s += u;
        }
        if (threadIdx.x == blockIdx.x) sboff = s - v;   // exclusive prefix
    }
    __syncthreads();
    int i = blockIdx.x * 1024 + threadIdx.x;
    if (i == 0) row_off[0] = 0;
    if (i < N_NODES) {
        int r = lscan[i] + sboff;
        row_off[i + 1] = r;
        cursor[i] = r - cnt[i];
    }
}

__global__ __launch_bounds__(256) void scatter_kernel(const int* __restrict__ ei,
        int* __restrict__ cursor, int* __restrict__ csr_src)
{
    int e = blockIdx.x * 256 + threadIdx.x;
    if (e >= E2) return;
    int s, d;
    if (e < N_EDGES) { s = ei[e]; d = ei[N_EDGES + e]; }
    else             { s = e - N_EDGES; d = s; }
    int pos = atomicAdd(&cursor[d], 1);
    csr_src[pos] = s;
}

// ---------------- bf16 MFMA GEMM, single-matrix 32-row tile, frag-order B ----------------
template<bool LN, bool OUTF, bool EMB>
__global__ __launch_bounds__(256) void gemm_mfma(
    const u16* __restrict__ Abf, const u16* __restrict__ A2bf,
    const float* __restrict__ Aln, const float* __restrict__ lnacc,
    const float* __restrict__ lng, const float* __restrict__ lnb,
    const int* __restrict__ xidx, const float* __restrict__ emb, u16* __restrict__ h_out,
    const u16* __restrict__ Wt1, const float* __restrict__ b1,
    float* __restrict__ C1f, u16* __restrict__ C1h,
    const u16* __restrict__ Wt2, const float* __restrict__ b2, u16* __restrict__ C2h,
    float* __restrict__ bnacc, int M)
{
    __shared__ u16 As[32 * 136];     // padded row stride 136 -> only free 2-way conflicts
    __shared__ float sLN[2];
    const u16*  Wt   = blockIdx.y ? Wt2 : Wt1;
    const float* bias = blockIdx.y ? b2 : b1;
    u16*        Ch   = blockIdx.y ? C2h : C1h;
    int t = threadIdx.x;
    int m0 = blockIdx.x * 32;
    int lane = t & 63, w = t >> 6;
    int n16 = lane & 15, quad = lane >> 4;
    int c0 = w * 32;

    // fragment-order B load: lane-consecutive 16B chunks (coalesced)
    const bfrag* Wf = (const bfrag*)Wt;
    bfrag bW[2][4];
    #pragma unroll
    for (int c = 0; c < 2; c++)
        #pragma unroll
        for (int ks = 0; ks < 4; ks++)
            bW[c][ks] = Wf[((w * 2 + c) * 4 + ks) * 64 + lane];

    if (LN) {
        if (w == 0) {   // wave 0: reduce the 64 (sum,sumsq) partial slots
            float2 v = ((const float2*)lnacc)[lane];
            float s = v.x, ss = v.y;
            #pragma unroll
            for (int off = 32; off > 0; off >>= 1) {
                s += __shfl_xor(s, off); ss += __shfl_xor(ss, off);
            }
            if (lane == 0) {
                const float invM = 1.f / ((float)N_NODES * (float)D);
                float mu  = s * invM;
                float var = ss * invM - mu * mu;
                sLN[0] = mu;
                sLN[1] = rsqrtf(var + LN_EPS);
            }
        }
        __syncthreads();
        float mu = sLN[0], inv = sLN[1];
        #pragma unroll
        for (int i = 0; i < 4; i++) {
            int idx = t + 256 * i;           // 1024 float4 chunks
            int row = idx >> 5, c4 = idx & 31;
            int gr = m0 + row;
            float4 v = make_float4(0.f, 0.f, 0.f, 0.f);
            if (gr < M) v = ((const float4*)(Aln + (size_t)gr * D))[c4];
            float4 gv = ((const float4*)lng)[c4];
            float4 bv = ((const float4*)lnb)[c4];
            v.x = (v.x - mu) * inv * gv.x + bv.x; v.x = v.x > 0.f ? v.x : 0.f;
            v.y = (v.y - mu) * inv * gv.y + bv.y; v.y = v.y > 0.f ? v.y : 0.f;
            v.z = (v.z - mu) * inv * gv.z + bv.z; v.z = v.z > 0.f ? v.z : 0.f;
            v.w = (v.w - mu) * inv * gv.w + bv.w; v.w = v.w > 0.f ? v.w : 0.f;
            uint2 pk = make_uint2(pack2(v.x, v.y), pack2(v.z, v.w));
            *(uint2*)&As[row * 136 + c4 * 4] = pk;
        }
    } else if (EMB) {
        #pragma unroll
        for (int i = 0; i < 2; i++) {
            int idx = t + 256 * i;           // 512 chunks of 16B (8 bf16)
            int row = idx >> 4, c16 = idx & 15;
            int gr = m0 + row;
            uint4 v = make_uint4(0u, 0u, 0u, 0u);
            if (gr < M) {
                const float* er = emb + (size_t)xidx[gr] * D + c16 * 8;
                float4 e0 = ((const float4*)er)[0];
                float4 e1 = ((const float4*)er)[1];
                v.x = pack2(e0.x, e0.y); v.y = pack2(e0.z, e0.w);
                v.z = pack2(e1.x, e1.y); v.w = pack2(e1.z, e1.w);
                if (blockIdx.y == 0)      // persist h once for the final GEMM
                    ((uint4*)(h_out + (size_t)gr * 128))[c16] = v;
            }
            *(uint4*)&As[row * 136 + c16 * 8] = v;
        }
    } else {
        #pragma unroll
        for (int i = 0; i < 2; i++) {
            int idx = t + 256 * i;           // 512 chunks of 16B
            int row = idx >> 4, c16 = idx & 15;
            int gr = m0 + row;
            uint4 v = make_uint4(0u, 0u, 0u, 0u);
            if (gr < M) {
                v = ((const uint4*)(Abf + (size_t)gr * 128))[c16];
                if (A2bf) {
                    uint4 u = ((const uint4*)(A2bf + (size_t)gr * 128))[c16];
                    v.x = bfadd2(v.x, u.x); v.y = bfadd2(v.y, u.y);
                    v.z = bfadd2(v.z, u.z); v.w = bfadd2(v.w, u.w);
                }
            }
            *(uint4*)&As[row * 136 + c16 * 8] = v;
        }
    }
    __syncthreads();

    f32x4 zero = {0.f, 0.f, 0.f, 0.f};
    f32x4 acc[2][2] = {{zero, zero}, {zero, zero}};
    #pragma unroll
    for (int ks = 0; ks < 4; ks++) {
        bfrag a[2];
        #pragma unroll
        for (int r = 0; r < 2; r++)
            a[r] = *(const bfrag*)&As[(r * 16 + n16) * 136 + ks * 32 + quad * 8];
        #pragma unroll
        for (int r = 0; r < 2; r++)
            #pragma unroll
            for (int c = 0; c < 2; c++)
                acc[r][c] = __builtin_amdgcn_mfma_f32_16x16x32_bf16(a[r], bW[c][ks], acc[r][c], 0, 0, 0);
    }

    float bv[2] = { bias[c0 + n16], bias[c0 + 16 + n16] };
    float bns[2] = {0.f, 0.f}, bnss[2] = {0.f, 0.f};
    #pragma unroll
    for (int r = 0; r < 2; r++)
        #pragma unroll
        for (int c = 0; c < 2; c++)
            #pragma unroll
            for (int reg = 0; reg < 4; reg++) {
                int grow = m0 + r * 16 + quad * 4 + reg;
                if (grow < M) {
                    float val = acc[r][c][reg] + bv[c];
                    int col = c0 + c * 16 + n16;
                    if (OUTF) {
                        C1f[(size_t)grow * 128 + col] = val;
                        bns[c] += val; bnss[c] += val * val;
                    } else {
                        Ch[(size_t)grow * 128 + col] = f2bf(val);
                    }
                }
            }
    if (OUTF) {
        // reduce per-column partials over quads (rows), then 16-slot spread atomics
        #pragma unroll
        for (int c = 0; c < 2; c++) {
            #pragma unroll
            for (int msk = 16; msk <= 32; msk <<= 1) {
                bns[c]  += __shfl_xor(bns[c], msk);
                bnss[c] += __shfl_xor(bnss[c], msk);
            }
        }
        if (quad == 0) {
            float* base = bnacc + (size_t)(blockIdx.x & 15) * 256;
            #pragma unroll
            for (int c = 0; c < 2; c++) {
                int col = c0 + c * 16 + n16;
                atomicAdd(&base[col], bns[c]);
                atomicAdd(&base[128 + col], bnss[c]);
            }
        }
    }
}

// ---------------- GATv2 edge phase (R8 form + NT hints — best measured 51.9us) ----------------
// Commutative no-max softmax; 16-lane group per edge, 4 in flight; DPP score reduce.
__global__ __launch_bounds__(256) void gat_agg(
    const u16* __restrict__ xl, const u16* __restrict__ xr,
    const int* __restrict__ row_off, const int* __restrict__ csr_src,
    const float* __restrict__ att, const float* __restrict__ conv_bias,
    float* __restrict__ xg, u16* __restrict__ xg_bf, float* __restrict__ lnacc)
{
    int wave = threadIdx.x >> 6, lane = threadIdx.x & 63;
    int node = blockIdx.x * 4 + wave;          // 7500*4 == 30000 exactly
    int g = lane >> 4, q = lane & 15;

    u32x4 rr = __builtin_nontemporal_load((const u32x4*)(xr + (size_t)node * 128) + q);
    float4 r0 = make_float4(bflo(rr.x), bfhi(rr.x), bflo(rr.y), bfhi(rr.y));
    float4 r1 = make_float4(bflo(rr.z), bfhi(rr.z), bflo(rr.w), bfhi(rr.w));
    float4 av0 = ((const float4*)att)[2 * q];
    float4 av1 = ((const float4*)att)[2 * q + 1];

    int s0 = row_off[node], s1 = row_off[node + 1];
    float denom = 0.f;
    float4 a0 = make_float4(0.f, 0.f, 0.f, 0.f), a1 = a0;

    #pragma unroll 4
    for (int s = s0 + g; s < s1; s += 4) {
        int src = csr_src[s];
        uint4 raw = *(const uint4*)(xl + (size_t)src * 128 + q * 8);
        float4 v0 = make_float4(bflo(raw.x), bfhi(raw.x), bflo(raw.y), bfhi(raw.y));
        float4 v1 = make_float4(bflo(raw.z), bfhi(raw.z), bflo(raw.w), bfhi(raw.w));
        float pr = 0.f, tt;
        tt = v0.x + r0.x; tt = tt > 0.f ? tt : NEG_SLOPE * tt; pr += av0.x * tt;
        tt = v0.y + r0.y; tt = tt > 0.f ? tt : NEG_SLOPE * tt; pr += av0.y * tt;
        tt = v0.z + r0.z; tt = tt > 0.f ? tt : NEG_SLOPE * tt; pr += av0.z * tt;
        tt = v0.w + r0.w; tt = tt > 0.f ? tt : NEG_SLOPE * tt; pr += av0.w * tt;
        tt = v1.x + r1.x; tt = tt > 0.f ? tt : NEG_SLOPE * tt; pr += av1.x * tt;
        tt = v1.y + r1.y; tt = tt > 0.f ? tt : NEG_SLOPE * tt; pr += av1.y * tt;
        tt = v1.z + r1.z; tt = tt > 0.f ? tt : NEG_SLOPE * tt; pr += av1.z * tt;
        tt = v1.w + r1.w; tt = tt > 0.f ? tt : NEG_SLOPE * tt; pr += av1.w * tt;
        pr = red16_dpp(pr);                     // 16-lane sum at VALU speed
        float wv = __expf(pr);
        denom += wv;
        a0.x += wv * v0.x; a0.y += wv * v0.y; a0.z += wv * v0.z; a0.w += wv * v0.w;
        a1.x += wv * v1.x; a1.y += wv * v1.y; a1.z += wv * v1.z; a1.w += wv * v1.w;
    }

    // merge the 4 groups (all commutative sums)
    #pragma unroll
    for (int msk = 16; msk <= 32; msk <<= 1) {
        denom += __shfl_xor(denom, msk);
        a0.x += __shfl_xor(a0.x, msk); a0.y += __shfl_xor(a0.y, msk);
        a0.z += __shfl_xor(a0.z, msk); a0.w += __shfl_xor(a0.w, msk);
        a1.x += __shfl_xor(a1.x, msk); a1.y += __shfl_xor(a1.y, msk);
        a1.z += __shfl_xor(a1.z, msk); a1.w += __shfl_xor(a1.w, msk);
    }

    float4 cb0 = ((const float4*)conv_bias)[2 * q];
    float4 cb1 = ((const float4*)conv_bias)[2 * q + 1];
    float inv = 1.f / denom;
    float4 o0, o1;
    o0.x = a0.x * inv + cb0.x; o0.y = a0.y * inv + cb0.y;
    o0.z = a0.z * inv + cb0.z; o0.w = a0.w * inv + cb0.w;
    o1.x = a1.x * inv + cb1.x; o1.y = a1.y * inv + cb1.y;
    o1.z = a1.z * inv + cb1.z; o1.w = a1.w * inv + cb1.w;

    if (xg_bf) {                 // last layer: bf16 only (feeds final MFMA GEMM)
        if (g == 0) {
            u32x4 pk = { pack2(o0.x, o0.y), pack2(o0.z, o0.w),
                         pack2(o1.x, o1.y), pack2(o1.z, o1.w) };
            __builtin_nontemporal_store(pk, (u32x4*)(xg_bf + (size_t)node * 128) + q);
        }
    } else {                     // layers 0..4: fp32 (LN applied by next gemm) + LN stats
        if (g == 0) {
            f32x4 w0 = { o0.x, o0.y, o0.z, o0.w };
            f32x4 w1 = { o1.x, o1.y, o1.z, o1.w };
            __builtin_nontemporal_store(w0, (f32x4*)(xg + (size_t)node * 128) + 2 * q);
            __builtin_nontemporal_store(w1, (f32x4*)(xg + (size_t)node * 128) + 2 * q + 1);
        }
        float s  = o0.x + o0.y + o0.z + o0.w + o1.x + o1.y + o1.z + o1.w;
        float ss = o0.x*o0.x + o0.y*o0.y + o0.z*o0.z + o0.w*o0.w
                 + o1.x*o1.x + o1.y*o1.y + o1.z*o1.z + o1.w*o1.w;
        s  = red16_dpp(s);
        ss = red16_dpp(ss);
        __shared__ float sred[8];
        if (lane == 0) { sred[wave] = s; sred[4 + wave] = ss; }
        __syncthreads();
        if (threadIdx.x == 0) {
            int slot = blockIdx.x & 63;   // 64-slot spread vs same-address serialization
            atomicAdd(&lnacc[2 * slot],     sred[0] + sred[1] + sred[2] + sred[3]);
            atomicAdd(&lnacc[2 * slot + 1], sred[4] + sred[5] + sred[6] + sred[7]);
        }
    }
}

// ---------------- BatchNorm1d apply (stats pre-accumulated by final GEMM) ----------------
__global__ __launch_bounds__(256) void bn_apply(float* __restrict__ out, const float* __restrict__ acc,
        const float* __restrict__ g, const float* __restrict__ b)
{
    int idx = blockIdx.x * 256 + threadIdx.x;
    if (idx >= N_NODES * 32) return;
    int c4 = idx & 31;
    float4 s1 = make_float4(0.f, 0.f, 0.f, 0.f), s2 = s1;
    #pragma unroll
    for (int slot = 0; slot < 16; slot++) {
        float4 a = ((const float4*)(acc + slot * 256))[c4];
        float4 d = ((const float4*)(acc + slot * 256 + 128))[c4];
        s1.x += a.x; s1.y += a.y; s1.z += a.z; s1.w += a.w;
        s2.x += d.x; s2.y += d.y; s2.z += d.z; s2.w += d.w;
    }
    float4 gv = ((const float4*)g)[c4];
    float4 bv = ((const float4*)b)[c4];
    float4 v = ((float4*)out)[idx];
    const float invN = 1.f / (float)N_NODES;
    float mu, var, inv;
    mu = s1.x * invN; var = s2.x * invN - mu * mu; inv = rsqrtf(var + LN_EPS);
    v.x = (v.x - mu) * inv * gv.x + bv.x;
    mu = s1.y * invN; var = s2.y * invN - mu * mu; inv = rsqrtf(var + LN_EPS);
    v.y = (v.y - mu) * inv * gv.y + bv.y;
    mu = s1.z * invN; var = s2.z * invN - mu * mu; inv = rsqrtf(var + LN_EPS);
    v.z = (v.z - mu) * inv * gv.z + bv.z;
    mu = s1.w * invN; var = s2.w * invN - mu * mu; inv = rsqrtf(var + LN_EPS);
    v.w = (v.w - mu) * inv * gv.w + bv.w;
    ((float4*)out)[idx] = v;
}

extern "C" void kernel_launch(void* const* d_in, const int* in_sizes, int n_in,
                              void* d_out, int out_size, void* d_ws, size_t ws_size,
                              hipStream_t stream)
{
    const int*   x    = (const int*)d_in[0];
    const int*   ei   = (const int*)d_in[1];
    const float* emb  = (const float*)d_in[2];
    const float* Wl   = (const float*)d_in[3];
    const float* bl   = (const float*)d_in[4];
    const float* Wr   = (const float*)d_in[5];
    const float* br   = (const float*)d_in[6];
    const float* att  = (const float*)d_in[7];
    const float* cbias= (const float*)d_in[8];
    const float* lng  = (const float*)d_in[9];
    const float* lnb  = (const float*)d_in[10];
    const float* linW = (const float*)d_in[11];
    const float* linb = (const float*)d_in[12];
    const float* bng  = (const float*)d_in[13];
    const float* bnb  = (const float*)d_in[14];
    float* out = (float*)d_out;

    char* p = (char*)d_ws;
    float* xg    = (float*)p; p += (size_t)N_NODES * D * 4;
    u16*   xl_bf = (u16*)p;   p += (size_t)N_NODES * D * 2;
    u16*   xr_bf = (u16*)p;   p += (size_t)N_NODES * D * 2;
    u16*   xg_bf = (u16*)p;   p += (size_t)N_NODES * D * 2;
    u16*   h_bf  = (u16*)p;   p += (size_t)N_NODES * D * 2;
    u16*   wt    = (u16*)p;   p += (size_t)13 * 16384 * 2;
    int* cnt     = (int*)p; p += ((N_NODES * 4 + 255) / 256) * 256;
    int* lscan   = (int*)p; p += ((N_NODES * 4 + 255) / 256) * 256;
    int* row_off = (int*)p; p += (((N_NODES + 1) * 4 + 255) / 256) * 256;
    int* cursor  = (int*)p; p += ((N_NODES * 4 + 255) / 256) * 256;
    int* csr_src = (int*)p; p += ((E2 * 4 + 255) / 256) * 256;
    int* bsum    = (int*)p; p += 256;
    float* accs  = (float*)p; p += 20480;
    // accs layout (floats): LN layer i partials at [i*128 .. i*128+128) as 64x float2 (i<5);
    // BN 16-slot column stats at [640 .. 640+4096)

    hipMemsetAsync(cnt, 0, N_NODES * 4, stream);
    hipMemsetAsync(accs, 0, (640 + 4096) * 4, stream);

    wt_convert<<<13, 256, 0, stream>>>(Wl, Wr, linW, wt);
    hist_kernel<<<(E2 + 255) / 256, 256, 0, stream>>>(ei, cnt);
    scan1_kernel<<<30, 1024, 0, stream>>>(cnt, lscan, bsum);
    scan3_kernel<<<30, 1024, 0, stream>>>(lscan, bsum, cnt, row_off, cursor);
    scatter_kernel<<<(E2 + 255) / 256, 256, 0, stream>>>(ei, cursor, csr_src);

    const int GX = (N_NODES + 31) / 32;   // 938
    for (int i = 0; i < LAYERS; i++) {
        if (i == 0) {
            gemm_mfma<false, false, true><<<dim3(GX, 2), 256, 0, stream>>>(
                nullptr, nullptr, nullptr, nullptr, nullptr, nullptr,
                x, emb, h_bf,
                wt + (size_t)0 * 16384, bl + 0, nullptr, xl_bf,
                wt + (size_t)1 * 16384, br + 0, xr_bf, nullptr, N_NODES);
        } else {
            gemm_mfma<true, false, false><<<dim3(GX, 2), 256, 0, stream>>>(
                nullptr, nullptr, xg, accs + (i - 1) * 128,
                lng + (size_t)(i - 1) * D, lnb + (size_t)(i - 1) * D,
                nullptr, nullptr, nullptr,
                wt + (size_t)(2 * i) * 16384, bl + i * D, nullptr, xl_bf,
                wt + (size_t)(2 * i + 1) * 16384, br + i * D, xr_bf, nullptr, N_NODES);
        }
        gat_agg<<<7500, 256, 0, stream>>>(xl_bf, xr_bf, row_off, csr_src,
            att + i * D, cbias + i * D, xg,
            (i == LAYERS - 1) ? xg_bf : nullptr,
            (i < LAYERS - 1) ? (accs + i * 128) : nullptr);
    }
    gemm_mfma<false, true, false><<<dim3(GX, 1), 256, 0, stream>>>(
        xg_bf, h_bf, nullptr, nullptr, nullptr, nullptr,
        nullptr, nullptr, nullptr,
        wt + (size_t)12 * 16384, linb, out, nullptr,
        nullptr, nullptr, nullptr, accs + 640, N_NODES);
    bn_apply<<<3750, 256, 0, stream>>>(out, accs + 640, bng, bnb);
}